// Round 1
// baseline (1595.284 us; speedup 1.0000x reference)
//
#include <hip/hip_runtime.h>
#include <hip/hip_bf16.h>

// Problem: temporal warp-difference.
// x: (32,3,720,1280) f32, flow: (30,2,720,1280) f32
// out: (30,6,720,1280) f32
//   out[n, c  ] = x[n+1,c] - x[n+2, c, clip(round(h+flow[n,0])), clip(round(w+flow[n,1]))]
//   out[n, 3+c] = x[n+1,c] - x[n,   c, clip(round(h+flow[29-n,0])), clip(round(w+flow[29-n,1]))]
// Memory-bound: ~2.1 GB total traffic -> ~335 us floor at 6.3 TB/s.

#define TT 32
#define CC 3
#define HH 720
#define WW 1280
#define NN (TT - 2)

__device__ __forceinline__ int clampi(int v, int lo, int hi) {
    return v < lo ? lo : (v > hi ? hi : v);
}

__global__ __launch_bounds__(256) void warp_diff_kernel(
    const float* __restrict__ x,
    const float* __restrict__ flow,
    float* __restrict__ out)
{
    const int WQ = WW / 4;                 // 320 quads per row
    int idx = blockIdx.x * blockDim.x + threadIdx.x;
    const int total = NN * HH * WQ;
    if (idx >= total) return;

    int wq = idx % WQ;
    int t  = idx / WQ;
    int h  = t % HH;
    int n  = t / HH;
    int w0 = wq * 4;

    const size_t HW = (size_t)HH * WW;
    const size_t rowoff = (size_t)h * WW + w0;

    // flow loads (vectorized, coalesced)
    const float4 fdx = *(const float4*)(flow + ((size_t)n * 2 + 0) * HW + rowoff);
    const float4 fdy = *(const float4*)(flow + ((size_t)n * 2 + 1) * HW + rowoff);
    const float4 bdx = *(const float4*)(flow + ((size_t)(NN - 1 - n) * 2 + 0) * HW + rowoff);
    const float4 bdy = *(const float4*)(flow + ((size_t)(NN - 1 - n) * 2 + 1) * HW + rowoff);

    // round half-to-even (jnp.round / np.round semantics) then clip.
    // rintf uses RNE (the GPU default rounding mode) -> matches.
    float fh = (float)h;
    int ixf[4], iyf[4], ixb[4], iyb[4];
    {
        const float fdxv[4] = {fdx.x, fdx.y, fdx.z, fdx.w};
        const float fdyv[4] = {fdy.x, fdy.y, fdy.z, fdy.w};
        const float bdxv[4] = {bdx.x, bdx.y, bdx.z, bdx.w};
        const float bdyv[4] = {bdy.x, bdy.y, bdy.z, bdy.w};
#pragma unroll
        for (int j = 0; j < 4; ++j) {
            float fw = (float)(w0 + j);
            ixf[j] = clampi((int)rintf(fh + fdxv[j]), 0, HH - 1);
            iyf[j] = clampi((int)rintf(fw + fdyv[j]), 0, WW - 1);
            ixb[j] = clampi((int)rintf(fh + bdxv[j]), 0, HH - 1);
            iyb[j] = clampi((int)rintf(fw + bdyv[j]), 0, WW - 1);
        }
    }

    // precompute gather offsets (same for all channels)
    size_t gf[4], gb[4];
#pragma unroll
    for (int j = 0; j < 4; ++j) {
        gf[j] = (size_t)ixf[j] * WW + iyf[j];
        gb[j] = (size_t)ixb[j] * WW + iyb[j];
    }

    const float* xc_base = x + ((size_t)(n + 1) * CC) * HW + rowoff;
    const float* xf_base = x + ((size_t)(n + 2) * CC) * HW;
    const float* xb_base = x + ((size_t)(n + 0) * CC) * HW;
    float* out_f = out + ((size_t)n * 6) * HW + rowoff;
    float* out_b = out_f + 3 * HW;

#pragma unroll
    for (int c = 0; c < CC; ++c) {
        const float4 vc = *(const float4*)(xc_base + (size_t)c * HW);
        const float* xf = xf_base + (size_t)c * HW;
        const float* xb = xb_base + (size_t)c * HW;

        float4 of, ob;
        of.x = vc.x - xf[gf[0]];
        of.y = vc.y - xf[gf[1]];
        of.z = vc.z - xf[gf[2]];
        of.w = vc.w - xf[gf[3]];
        ob.x = vc.x - xb[gb[0]];
        ob.y = vc.y - xb[gb[1]];
        ob.z = vc.z - xb[gb[2]];
        ob.w = vc.w - xb[gb[3]];

        *(float4*)(out_f + (size_t)c * HW) = of;
        *(float4*)(out_b + (size_t)c * HW) = ob;
    }
}

extern "C" void kernel_launch(void* const* d_in, const int* in_sizes, int n_in,
                              void* d_out, int out_size, void* d_ws, size_t ws_size,
                              hipStream_t stream) {
    const float* x    = (const float*)d_in[0];
    const float* flow = (const float*)d_in[1];
    float* out = (float*)d_out;

    const int WQ = WW / 4;
    const int total = NN * HH * WQ;      // 30*720*320 = 6,912,000 threads
    const int block = 256;
    const int grid = (total + block - 1) / block;
    warp_diff_kernel<<<grid, block, 0, stream>>>(x, flow, out);
}